// Round 8
// baseline (194.075 us; speedup 1.0000x reference)
//
#include <hip/hip_runtime.h>
#include <hip/hip_fp16.h>

// SpMM scatter: out[row[e]] += values[e] * x[col[e]],  row sorted, D=64.
// R8: EDGE-centric. 256 edges/block (4 waves), 6250 blocks -> 25k waves
// (4x fewer than node-per-wave). Per wave: 3 preloads + 8 h8 gathers issued
// upfront (one latency round covers 64 edges); per-lane running accumulate
// with flush->LDS (ds_add_f32) on row change (rows sorted -> ~1-2 flushes
// per 8-edge lane window). Block write phase: interior nodes (sole owner,
// contiguous edges) = plain float4 store; 2 boundary nodes = atomicAdd onto
// pre-zeroed out. Prep: fp16 convert of x + zero out (no row_ptr needed).

constexpr int D       = 64;
constexpr int DV      = 16;   // float4 chunks per out row
constexpr int DH8     = 8;    // 16B h8 chunks per fp16 x row (128B)
constexpr int EPB     = 256;  // edges per block
constexpr int MAXSPAN = 96;   // fast-path node-span cap (24 KB LDS)

struct __align__(16) h8 { __half2 a, b, c, d; };

__global__ __launch_bounds__(256) void prep_kernel(
    const float4* __restrict__ x4,
    h8* __restrict__ xh,
    float4* __restrict__ out4,
    int n8, int nOut4)
{
    const int i = blockIdx.x * blockDim.x + threadIdx.x;
    if (i < nOut4) out4[i] = float4{0.f, 0.f, 0.f, 0.f};   // zero out (for atomics/empties)
    if (i < n8) {                                          // fp32 -> fp16, 32B in / 16B out
        const float4 lo = x4[2 * i];
        const float4 hi = x4[2 * i + 1];
        h8 h;
        h.a = __float22half2_rn(make_float2(lo.x, lo.y));
        h.b = __float22half2_rn(make_float2(lo.z, lo.w));
        h.c = __float22half2_rn(make_float2(hi.x, hi.y));
        h.d = __float22half2_rn(make_float2(hi.z, hi.w));
        xh[i] = h;
    }
}

__global__ __launch_bounds__(256) void spmm_edge_lds(
    const int* __restrict__ row,
    const int* __restrict__ col,
    const float* __restrict__ val,
    const h8* __restrict__ xh,
    float* __restrict__ out,
    int nEdges, int nNodes)
{
    __shared__ __align__(16) float lds[MAXSPAN * D];   // 24 KB
    const int tid  = threadIdx.x;
    const int lane = tid & 63;
    const int wg   = tid >> 6;          // wave index in block
    const int sub  = lane & 7;          // 16B h8 chunk within x row
    const int base = lane & 56;         // 8*group: this group's edge-slot base
    const int BPE  = blockIdx.x * EPB;  // block edge base
    const int lastE = nEdges - 1;

    const int r0   = row[min(BPE, lastE)];              // uniform -> scalar
    const int rEnd = row[min(BPE + EPB - 1, lastE)];
    const int span = rEnd - r0 + 1;

    // per-wave preload of 64 contiguous edges (3 VMEM); padded lanes: v=0,
    // r clamps to row[lastE] (== rEnd of the last block -> in-span, adds 0)
    const int  eL = BPE + wg * 64 + lane;
    const bool ok = eL < nEdges;
    const int   rr = row[min(eL, lastE)];
    const int   cc = ok ? col[eL] : 0;
    const float vv = ok ? val[eL] : 0.f;

    if (span <= MAXSPAN) {
        for (int i = tid; i < span * D; i += EPB) lds[i] = 0.f;
        __syncthreads();

        // all 8 gathers upfront: one latency round for the wave's 64 edges
        int cj[8];
        #pragma unroll
        for (int j = 0; j < 8; ++j) cj[j] = __shfl(cc, base + j, 64);
        h8 p[8];
        #pragma unroll
        for (int j = 0; j < 8; ++j) p[j] = xh[(size_t)cj[j] * DH8 + sub];

        // per-lane running accumulate over the group's 8 contiguous edges;
        // flush to LDS on row change (group-uniform condition, rows sorted)
        float acc[8] = {0.f,0.f,0.f,0.f,0.f,0.f,0.f,0.f};
        int rprev = __shfl(rr, base, 64);
        #pragma unroll
        for (int j = 0; j < 8; ++j) {
            const int   rj = __shfl(rr, base + j, 64);
            const float vj = __shfl(vv, base + j, 64);
            if (rj != rprev) {
                float* dst = &lds[(rprev - r0) * D + sub * 8];
                #pragma unroll
                for (int k = 0; k < 8; ++k) { atomicAdd(&dst[k], acc[k]); acc[k] = 0.f; }
                rprev = rj;
            }
            float2 f;
            f = __half22float2(p[j].a); acc[0] = fmaf(vj, f.x, acc[0]); acc[1] = fmaf(vj, f.y, acc[1]);
            f = __half22float2(p[j].b); acc[2] = fmaf(vj, f.x, acc[2]); acc[3] = fmaf(vj, f.y, acc[3]);
            f = __half22float2(p[j].c); acc[4] = fmaf(vj, f.x, acc[4]); acc[5] = fmaf(vj, f.y, acc[5]);
            f = __half22float2(p[j].d); acc[6] = fmaf(vj, f.x, acc[6]); acc[7] = fmaf(vj, f.y, acc[7]);
        }
        {   // final flush
            float* dst = &lds[(rprev - r0) * D + sub * 8];
            #pragma unroll
            for (int k = 0; k < 8; ++k) atomicAdd(&dst[k], acc[k]);
        }
        __syncthreads();

        // write phase: interior = sole owner -> plain store; boundary (r0,
        // rEnd may be shared with neighbor blocks) -> atomicAdd onto zeroed out
        for (int idx = tid; idx < span * DV; idx += EPB) {
            const int li = idx >> 4, ch = idx & 15;
            const int node = r0 + li;
            const float4 w = *(const float4*)&lds[li * D + ch * 4];
            float* dst = &out[(size_t)node * D + ch * 4];
            if (li == 0 || li == span - 1) {
                atomicAdd(&dst[0], w.x); atomicAdd(&dst[1], w.y);
                atomicAdd(&dst[2], w.z); atomicAdd(&dst[3], w.w);
            } else {
                *(float4*)dst = w;
            }
        }
    } else {
        // pathological span (statistically never): direct global atomics
        #pragma unroll
        for (int j = 0; j < 8; ++j) {
            const int   c  = __shfl(cc, base + j, 64);
            const int   rj = __shfl(rr, base + j, 64);
            const float vj = __shfl(vv, base + j, 64);
            const h8 pp = xh[(size_t)c * DH8 + sub];
            if (vj != 0.f) {
                float2 f; float t[8];
                f = __half22float2(pp.a); t[0] = vj * f.x; t[1] = vj * f.y;
                f = __half22float2(pp.b); t[2] = vj * f.x; t[3] = vj * f.y;
                f = __half22float2(pp.c); t[4] = vj * f.x; t[5] = vj * f.y;
                f = __half22float2(pp.d); t[6] = vj * f.x; t[7] = vj * f.y;
                float* dst = &out[(size_t)rj * D + sub * 8];
                #pragma unroll
                for (int k = 0; k < 8; ++k) atomicAdd(&dst[k], t[k]);
            }
        }
    }
}

// Fallback (ws too small): single-dispatch p-search kernel, fp32 (R3-proven).
__global__ __launch_bounds__(256) void spmm_psearch(
    const int* __restrict__ row,
    const int* __restrict__ col,
    const float* __restrict__ val,
    const float4* __restrict__ x4,
    float4* __restrict__ out4,
    int nEdges, int nNodes)
{
    const int wid = (blockIdx.x * blockDim.x + threadIdx.x) >> 6;
    if (wid >= nNodes) return;
    const int lane  = threadIdx.x & 63;
    const int group = lane >> 4;
    const int sub   = lane & 15;

    int lo = 0, hi = nEdges;
    const int t0 = wid;
    while (hi > lo) {
        const int span = hi - lo + 1;
        if (span <= 64) {
            const int idx = lo + lane;
            const bool lt = (idx <= hi) && (idx < nEdges) && (row[idx] < t0);
            lo += __popcll(__ballot(lt));
            break;
        }
        const int step = (span + 63) >> 6;
        const int idx  = lo + lane * step;
        const bool lt  = (idx <= hi) && (idx < nEdges) && (row[idx] < t0);
        const int  c   = __popcll(__ballot(lt));
        if (c == 0) { hi = lo; break; }
        const int new_lo = lo + (c - 1) * step + 1;
        if (c < 64) hi = lo + c * step;
        lo = new_lo;
    }
    const int start = lo;
    const int t1 = wid + 1;
    int end = start;
    for (;;) {
        const int idx = end + lane;
        const bool lt = (idx < nEdges) && (row[idx] < t1);
        const int  c  = __popcll(__ballot(lt));
        end += c;
        if (c < 64) break;
    }

    float4 acc = {0.f, 0.f, 0.f, 0.f};
    for (int e = start + group; e < end; e += 8) {
        const int e1 = e + 4;
        const int   c0 = col[e];
        const float v0 = val[e];
        int c1 = c0; float v1 = 0.f;
        if (e1 < end) { c1 = col[e1]; v1 = val[e1]; }
        const float4 x0 = x4[(size_t)c0 * DV + sub];
        const float4 x1 = x4[(size_t)c1 * DV + sub];
        acc.x = fmaf(v0, x0.x, acc.x); acc.y = fmaf(v0, x0.y, acc.y);
        acc.z = fmaf(v0, x0.z, acc.z); acc.w = fmaf(v0, x0.w, acc.w);
        acc.x = fmaf(v1, x1.x, acc.x); acc.y = fmaf(v1, x1.y, acc.y);
        acc.z = fmaf(v1, x1.z, acc.z); acc.w = fmaf(v1, x1.w, acc.w);
    }
    #pragma unroll
    for (int off = 16; off <= 32; off <<= 1) {
        acc.x += __shfl_xor(acc.x, off, 64);
        acc.y += __shfl_xor(acc.y, off, 64);
        acc.z += __shfl_xor(acc.z, off, 64);
        acc.w += __shfl_xor(acc.w, off, 64);
    }
    if (group == 0) out4[(size_t)wid * DV + sub] = acc;
}

extern "C" void kernel_launch(void* const* d_in, const int* in_sizes, int n_in,
                              void* d_out, int out_size, void* d_ws, size_t ws_size,
                              hipStream_t stream)
{
    const int*    row  = (const int*)   d_in[0];
    const int*    col  = (const int*)   d_in[1];
    const float*  val  = (const float*) d_in[2];
    const float4* x4   = (const float4*)d_in[3];

    const int nEdges = in_sizes[0];
    const int nNodes = out_size / D;        // 100000
    const int n8     = nNodes * DH8;        // 800k h8 chunks
    const int nOut4  = nNodes * DV;         // 1.6M float4 out chunks

    const dim3 block(256);
    const size_t need = (size_t)nNodes * D * sizeof(__half);   // xh only

    if (ws_size >= need) {
        h8* xh = (h8*)d_ws;
        const int prep_n = (nOut4 > n8) ? nOut4 : n8;
        prep_kernel<<<dim3((prep_n + 255) / 256), block, 0, stream>>>(
            x4, xh, (float4*)d_out, n8, nOut4);
        spmm_edge_lds<<<dim3((nEdges + EPB - 1) / EPB), block, 0, stream>>>(
            row, col, val, xh, (float*)d_out, nEdges, nNodes);
    } else {
        spmm_psearch<<<dim3(((size_t)nNodes * 64 + 255) / 256), block, 0, stream>>>(
            row, col, val, x4, (float4*)d_out, nEdges, nNodes);
    }
}

// Round 9
// 123.172 us; speedup vs baseline: 1.5756x; 1.5756x over previous
//
#include <hip/hip_runtime.h>
#include <hip/hip_fp16.h>

// SpMM scatter: out[row[e]] += values[e] * x[col[e]],  row sorted, D=64.
// R9 = revert to R6 (best measured: 123.36 us total). Rationale:
//   R6/R5/R7 all ~123-125 us => main (~39us) sits at the random-gather
//   line-service floor: 1.6M edges x one 128B fp16 row-line each at
//   ~5.4 TB/s effective L2/L3 service. R8 (edge-centric LDS scatter)
//   regressed 3x: shfl/LDS-atomic/divergence costs dominate.
// Structure: TWO nodes per 64-lane wave (pair edge range contiguous, avg 32):
//   - one col/val preload pair serves both nodes        (2 VMEM / 2 nodes)
//   - fp16 gathers: 8 groups x 8 lanes x 16B (h8)       (8 edge-rows / instr)
//   - shfl repack -> ONE store instr for both 256B rows (1 VMEM / 2 nodes)
//   - row_ptr via uniform s_loads (scalar cache, no TA)
// Dispatch 1 (prep): x fp32->fp16 (h8) + row_ptr build, fused.

constexpr int D   = 64;
constexpr int DV  = 16;  // float4 chunks per out row
constexpr int DH8 = 8;   // 16B h8 chunks per fp16 x row (128B)

struct __align__(16) h8 { __half2 a, b, c, d; };

__global__ __launch_bounds__(256) void prep_kernel(
    const int* __restrict__ row,
    const float4* __restrict__ x4,
    h8* __restrict__ xh,
    int* __restrict__ row_ptr,
    int nEdges, int n8, int nNodes)
{
    const int i = blockIdx.x * blockDim.x + threadIdx.x;
    if (i < n8) {                       // fp32 -> fp16, 32B in / 16B out
        const float4 lo = x4[2 * i];
        const float4 hi = x4[2 * i + 1];
        h8 h;
        h.a = __float22half2_rn(make_float2(lo.x, lo.y));
        h.b = __float22half2_rn(make_float2(lo.z, lo.w));
        h.c = __float22half2_rn(make_float2(hi.x, hi.y));
        h.d = __float22half2_rn(make_float2(hi.z, hi.w));
        xh[i] = h;
    }
    if (i < nEdges) {                   // row_ptr build (R2-proven)
        const int r    = row[i];
        const int prev = (i == 0) ? -1 : row[i - 1];
        for (int n = prev + 1; n <= r; ++n) row_ptr[n] = i;
        if (i == nEdges - 1)
            for (int n = r + 1; n <= nNodes; ++n) row_ptr[n] = nEdges;
    }
}

__device__ __forceinline__ void fma_h8(const h8& p, float v, float4& a0, float4& a1)
{
    float2 f;
    f = __half22float2(p.a); a0.x = fmaf(v, f.x, a0.x); a0.y = fmaf(v, f.y, a0.y);
    f = __half22float2(p.b); a0.z = fmaf(v, f.x, a0.z); a0.w = fmaf(v, f.y, a0.w);
    f = __half22float2(p.c); a1.x = fmaf(v, f.x, a1.x); a1.y = fmaf(v, f.y, a1.y);
    f = __half22float2(p.d); a1.z = fmaf(v, f.x, a1.z); a1.w = fmaf(v, f.y, a1.w);
}

__global__ __launch_bounds__(256) void spmm_h8x2(
    const int* __restrict__ row_ptr,
    const int* __restrict__ col,
    const float* __restrict__ val,
    const h8* __restrict__ xh,
    float4* __restrict__ out4,
    int nPairs, int nNodes)
{
    const int pw = (blockIdx.x * blockDim.x + threadIdx.x) >> 6;   // node pair id
    if (pw >= nPairs) return;
    const int lane = threadIdx.x & 63;
    const int half = lane >> 5;        // 0/1 -> node 2*pw+half
    const int g    = (lane >> 3) & 3;  // group within half (4 groups x 8 lanes)
    const int sub  = lane & 7;         // 16B h8 chunk within x row

    const int upw = __builtin_amdgcn_readfirstlane(pw);
    const int n0  = upw * 2;
    const bool has1 = (n0 + 1) < nNodes;

    const int s0 = row_ptr[n0];                       // uniform -> s_load
    const int s1 = row_ptr[n0 + 1];
    const int s2 = has1 ? row_ptr[n0 + 2] : s1;
    const int d0 = s1 - s0;                           // deg of node0
    const int d1 = s2 - s1;                           // deg of node1
    const int span = s2 - s0;

    float4 a0 = {0.f, 0.f, 0.f, 0.f};
    float4 a1 = {0.f, 0.f, 0.f, 0.f};

    if (span <= 64) {
        // one preload pair serves both nodes: 2 VMEM for the wave
        const int  eL  = s0 + lane;
        const bool okL = eL < s2;
        const int   cv = okL ? col[eL] : 0;
        const float vv = okL ? val[eL] : 0.f;

        const int bh    = half ? d0 : 0;              // this half's slot base
        const int degh  = half ? d1 : d0;
        const int itmax = (max(d0, d1) + 3) >> 2;     // uniform loop count
        for (int it = 0; it < itmax; ++it) {
            const int  sl   = it * 4 + g;             // local edge index
            const bool ok   = sl < degh;
            const int  slot = min(bh + (ok ? sl : 0), 63);
            const int   c = __shfl(cv, slot, 64);     // col (or safe dummy 0)
            float       v = __shfl(vv, slot, 64);
            v = ok ? v : 0.f;
            const h8 p = xh[(size_t)c * DH8 + sub];   // 1 instr = 8 edge-rows
            fma_h8(p, v, a0, a1);
        }
    } else {
        // rare: pair spans >64 edges -> direct loads, 4 edges/iter per half
        const int bs = half ? s1 : s0;
        const int be = half ? s2 : s1;
        for (int e = bs + g; e < be; e += 4) {
            const int   c = col[e];                   // 8-lane broadcast load
            const float v = val[e];
            const h8 p = xh[(size_t)c * DH8 + sub];
            fma_h8(p, v, a0, a1);
        }
    }

    // reduce across the 4 groups within each 32-lane half (lanes ^8, ^16)
    #pragma unroll
    for (int off = 8; off <= 16; off <<= 1) {
        a0.x += __shfl_xor(a0.x, off, 64); a0.y += __shfl_xor(a0.y, off, 64);
        a0.z += __shfl_xor(a0.z, off, 64); a0.w += __shfl_xor(a0.w, off, 64);
        a1.x += __shfl_xor(a1.x, off, 64); a1.y += __shfl_xor(a1.y, off, 64);
        a1.z += __shfl_xor(a1.z, off, 64); a1.w += __shfl_xor(a1.w, off, 64);
    }

    // repack: lane 32h+s holds float4 chunks (2s,2s+1); move to lanes 32h+t,
    // t=0..15 each holding chunk t -> ONE wave-wide dwordx4 store, both rows.
    const int t   = lane & 31;
    const int src = (lane & 32) + (t >> 1);
    float4 b0, b1;
    b0.x = __shfl(a0.x, src, 64); b0.y = __shfl(a0.y, src, 64);
    b0.z = __shfl(a0.z, src, 64); b0.w = __shfl(a0.w, src, 64);
    b1.x = __shfl(a1.x, src, 64); b1.y = __shfl(a1.y, src, 64);
    b1.z = __shfl(a1.z, src, 64); b1.w = __shfl(a1.w, src, 64);
    const float4 r = (t & 1) ? b1 : b0;
    const int node = n0 + half;
    if (t < 16 && node < nNodes)
        out4[(size_t)node * DV + t] = r;
}

// Fallback (ws too small): single-dispatch p-search kernel, fp32 (R3-proven).
__global__ __launch_bounds__(256) void spmm_psearch(
    const int* __restrict__ row,
    const int* __restrict__ col,
    const float* __restrict__ val,
    const float4* __restrict__ x4,
    float4* __restrict__ out4,
    int nEdges, int nNodes)
{
    const int wid = (blockIdx.x * blockDim.x + threadIdx.x) >> 6;
    if (wid >= nNodes) return;
    const int lane  = threadIdx.x & 63;
    const int group = lane >> 4;
    const int sub   = lane & 15;

    int lo = 0, hi = nEdges;
    const int t0 = wid;
    while (hi > lo) {
        const int span = hi - lo + 1;
        if (span <= 64) {
            const int idx = lo + lane;
            const bool lt = (idx <= hi) && (idx < nEdges) && (row[idx] < t0);
            lo += __popcll(__ballot(lt));
            break;
        }
        const int step = (span + 63) >> 6;
        const int idx  = lo + lane * step;
        const bool lt  = (idx <= hi) && (idx < nEdges) && (row[idx] < t0);
        const int  c   = __popcll(__ballot(lt));
        if (c == 0) { hi = lo; break; }
        const int new_lo = lo + (c - 1) * step + 1;
        if (c < 64) hi = lo + c * step;
        lo = new_lo;
    }
    const int start = lo;
    const int t1 = wid + 1;
    int end = start;
    for (;;) {
        const int idx = end + lane;
        const bool lt = (idx < nEdges) && (row[idx] < t1);
        const int  c  = __popcll(__ballot(lt));
        end += c;
        if (c < 64) break;
    }

    float4 acc = {0.f, 0.f, 0.f, 0.f};
    for (int e = start + group; e < end; e += 8) {
        const int e1 = e + 4;
        const int   c0 = col[e];
        const float v0 = val[e];
        int c1 = c0; float v1 = 0.f;
        if (e1 < end) { c1 = col[e1]; v1 = val[e1]; }
        const float4 x0 = x4[(size_t)c0 * DV + sub];
        const float4 x1 = x4[(size_t)c1 * DV + sub];
        acc.x = fmaf(v0, x0.x, acc.x); acc.y = fmaf(v0, x0.y, acc.y);
        acc.z = fmaf(v0, x0.z, acc.z); acc.w = fmaf(v0, x0.w, acc.w);
        acc.x = fmaf(v1, x1.x, acc.x); acc.y = fmaf(v1, x1.y, acc.y);
        acc.z = fmaf(v1, x1.z, acc.z); acc.w = fmaf(v1, x1.w, acc.w);
    }
    #pragma unroll
    for (int off = 16; off <= 32; off <<= 1) {
        acc.x += __shfl_xor(acc.x, off, 64);
        acc.y += __shfl_xor(acc.y, off, 64);
        acc.z += __shfl_xor(acc.z, off, 64);
        acc.w += __shfl_xor(acc.w, off, 64);
    }
    if (group == 0) out4[(size_t)wid * DV + sub] = acc;
}

extern "C" void kernel_launch(void* const* d_in, const int* in_sizes, int n_in,
                              void* d_out, int out_size, void* d_ws, size_t ws_size,
                              hipStream_t stream)
{
    const int*    row  = (const int*)   d_in[0];
    const int*    col  = (const int*)   d_in[1];
    const float*  val  = (const float*) d_in[2];
    const float4* x4   = (const float4*)d_in[3];
    float4*       out4 = (float4*)d_out;

    const int nEdges = in_sizes[0];
    const int nNodes = out_size / D;            // 100000
    const int n8     = nNodes * DH8;            // 800k h8 chunks
    const int nPairs = (nNodes + 1) / 2;        // 50000

    const dim3 block(256);

    const size_t rp_bytes = (size_t)(nNodes + 1) * sizeof(int);
    const size_t xh_off   = (rp_bytes + 255) & ~(size_t)255;
    const size_t need     = xh_off + (size_t)nNodes * D * sizeof(__half);

    if (ws_size >= need) {
        int* row_ptr = (int*)d_ws;
        h8*  xh      = (h8*)((char*)d_ws + xh_off);
        const int prep_n = (nEdges > n8) ? nEdges : n8;
        prep_kernel<<<dim3((prep_n + 255) / 256), block, 0, stream>>>(
            row, x4, xh, row_ptr, nEdges, n8, nNodes);
        spmm_h8x2<<<dim3(((size_t)nPairs * 64 + 255) / 256), block, 0, stream>>>(
            row_ptr, col, val, xh, out4, nPairs, nNodes);
    } else {
        spmm_psearch<<<dim3(((size_t)nNodes * 64 + 255) / 256), block, 0, stream>>>(
            row, col, val, x4, out4, nEdges, nNodes);
    }
}